// Round 1
// baseline (17.164 us; speedup 1.0000x reference)
//
#include <hip/hip_runtime.h>
#include <hip/hip_bf16.h>

#define NMOL 64
#define DIM 64
#define MTOT 8192
#define NPROP 452
#define LDSP 80   // LDS row stride in bf16 elems (160B: 16B-aligned, breaks 128B-stride conflicts)

typedef __attribute__((ext_vector_type(8))) short bf16x8;
typedef __attribute__((ext_vector_type(4))) short bf16x4;
typedef __attribute__((ext_vector_type(4))) float f32x4;

__device__ __forceinline__ unsigned short f2bf(float x) {
  union { float f; unsigned u; } v; v.f = x;
  unsigned r = v.u + 0x7FFFu + ((v.u >> 16) & 1u);   // round-to-nearest-even
  return (unsigned short)(r >> 16);
}

__global__ __launch_bounds__(256) void mgnn_kernel(
    const int* __restrict__ fp, const float* __restrict__ adj,
    const float* __restrict__ embed, const float* __restrict__ Wf,
    const float* __restrict__ bfv, const float* __restrict__ Wo,
    const float* __restrict__ bo, const float* __restrict__ Wp,
    const float* __restrict__ bp, float* __restrict__ out)
{
  __shared__ unsigned short A_s[64 * LDSP];        // adjacency block, [i][j]
  __shared__ unsigned short V_s[64 * LDSP];        // v, [i][k]
  __shared__ unsigned short HT_s[64 * LDSP];       // h^T, [d][j]
  __shared__ unsigned short WT_s[3][64 * LDSP];    // Wf^T, [d][k]
  __shared__ float molp[4][64];
  __shared__ float mol_s[64];

  const int t = threadIdx.x;
  const int b = blockIdx.x;
  const int lane = t & 63;
  const int w = t >> 6;        // wave 0..3 -> owns output row panel [16w,16w+16)
  const int c = lane & 15;
  const int g = lane >> 4;

  // ---- stage adjacency diagonal block + embedded node vectors (f32 -> bf16) ----
  {
    const int row = t >> 2;
    const int cq = (t & 3) << 4;
    const float* arow = adj + (size_t)(b * NMOL + row) * MTOT + (size_t)b * NMOL + cq;
    const int f = fp[b * NMOL + row];
    const float* erow = embed + (size_t)f * DIM + cq;
    float va[16], ve[16];
#pragma unroll
    for (int q = 0; q < 4; ++q) {
      const float4 xa = reinterpret_cast<const float4*>(arow)[q];
      const float4 xe = reinterpret_cast<const float4*>(erow)[q];
      va[4*q+0]=xa.x; va[4*q+1]=xa.y; va[4*q+2]=xa.z; va[4*q+3]=xa.w;
      ve[4*q+0]=xe.x; ve[4*q+1]=xe.y; ve[4*q+2]=xe.z; ve[4*q+3]=xe.w;
    }
    bf16x8 pa0, pa1, pe0, pe1;
#pragma unroll
    for (int i = 0; i < 8; ++i) {
      pa0[i] = (short)f2bf(va[i]);   pa1[i] = (short)f2bf(va[8+i]);
      pe0[i] = (short)f2bf(ve[i]);   pe1[i] = (short)f2bf(ve[8+i]);
    }
    *reinterpret_cast<bf16x8*>(&A_s[row * LDSP + cq])     = pa0;
    *reinterpret_cast<bf16x8*>(&A_s[row * LDSP + cq + 8]) = pa1;
    *reinterpret_cast<bf16x8*>(&V_s[row * LDSP + cq])     = pe0;
    *reinterpret_cast<bf16x8*>(&V_s[row * LDSP + cq + 8]) = pe1;
  }
  // ---- stage Wf[l] transposed: WT_s[l][d][k] = Wf[l][k][d] ----
#pragma unroll
  for (int l = 0; l < 3; ++l) {
    const int k = t >> 2;
    const int dq = (t & 3) << 4;
    const float* wrow = Wf + l * DIM * DIM + k * DIM + dq;
#pragma unroll
    for (int q = 0; q < 4; ++q) {
      const float4 x = reinterpret_cast<const float4*>(wrow)[q];
      WT_s[l][(dq + 4*q + 0) * LDSP + k] = f2bf(x.x);
      WT_s[l][(dq + 4*q + 1) * LDSP + k] = f2bf(x.y);
      WT_s[l][(dq + 4*q + 2) * LDSP + k] = f2bf(x.z);
      WT_s[l][(dq + 4*q + 3) * LDSP + k] = f2bf(x.w);
    }
  }
  __syncthreads();

  f32x4 acc[4];
  const int lrow_off = (w * 16 + c) * LDSP;   // LEFT-operand fragment row base

#pragma unroll 1
  for (int l = 0; l < 3; ++l) {
    // ---- matmul1: acc = v @ Wf[l] + bf[l]  (bias via C-init) ----
#pragma unroll
    for (int tc = 0; tc < 4; ++tc) {
      const float bias = bfv[l * DIM + tc * 16 + c];
      acc[tc][0] = bias; acc[tc][1] = bias; acc[tc][2] = bias; acc[tc][3] = bias;
    }
#pragma unroll
    for (int kh = 0; kh < 2; ++kh) {
      const int ko = kh * 32 + g * 8;
      const bf16x8 af = *reinterpret_cast<const bf16x8*>(&V_s[lrow_off + ko]);
#pragma unroll
      for (int tc = 0; tc < 4; ++tc) {
        const bf16x8 bb = *reinterpret_cast<const bf16x8*>(&WT_s[l][(tc * 16 + c) * LDSP + ko]);
        acc[tc] = __builtin_amdgcn_mfma_f32_16x16x32_bf16(af, bb, acc[tc], 0, 0, 0);
      }
    }
    // ---- relu (h stays f32 in acc); write h^T to LDS as bf16 ----
#pragma unroll
    for (int tc = 0; tc < 4; ++tc) {
      bf16x4 hp;
#pragma unroll
      for (int r = 0; r < 4; ++r) {
        const float h = fmaxf(acc[tc][r], 0.0f);
        acc[tc][r] = h;
        hp[r] = (short)f2bf(h);
      }
      // C/D: row = 16w + 4g + r, col = 16tc + c; h^T[col][row], 4 rows contiguous -> b64
      *reinterpret_cast<bf16x4*>(&HT_s[(tc * 16 + c) * LDSP + w * 16 + g * 4]) = hp;
    }
    __syncthreads();
    // ---- matmul2: acc += A @ h  (acc already holds h -> hs = h + A@h) ----
#pragma unroll
    for (int kh = 0; kh < 2; ++kh) {
      const int ko = kh * 32 + g * 8;
      const bf16x8 af = *reinterpret_cast<const bf16x8*>(&A_s[lrow_off + ko]);
#pragma unroll
      for (int tc = 0; tc < 4; ++tc) {
        const bf16x8 bb = *reinterpret_cast<const bf16x8*>(&HT_s[(tc * 16 + c) * LDSP + ko]);
        acc[tc] = __builtin_amdgcn_mfma_f32_16x16x32_bf16(af, bb, acc[tc], 0, 0, 0);
      }
    }
    // ---- row-wise L2 normalize (rows 16w+4g+r; cols spread over 16 lanes of group g) ----
    float ss[4] = {0.f, 0.f, 0.f, 0.f};
#pragma unroll
    for (int tc = 0; tc < 4; ++tc)
#pragma unroll
      for (int r = 0; r < 4; ++r) ss[r] += acc[tc][r] * acc[tc][r];
#pragma unroll
    for (int m = 1; m <= 8; m <<= 1) {
#pragma unroll
      for (int r = 0; r < 4; ++r) ss[r] += __shfl_xor(ss[r], m, 64);
    }
    float inv[4];
#pragma unroll
    for (int r = 0; r < 4; ++r) inv[r] = rsqrtf(fmaxf(ss[r], 1e-24f));
#pragma unroll
    for (int tc = 0; tc < 4; ++tc)
#pragma unroll
      for (int r = 0; r < 4; ++r) acc[tc][r] *= inv[r];

    if (l < 2) {
      // write v' back for next layer's matmul1 (strided scalar bf16 stores)
#pragma unroll
      for (int tc = 0; tc < 4; ++tc)
#pragma unroll
        for (int r = 0; r < 4; ++r)
          V_s[(w * 16 + g * 4 + r) * LDSP + tc * 16 + c] = f2bf(acc[tc][r]);
      __syncthreads();
    }
  }

  // ---- sum-pool over the molecule's 64 nodes (from f32 fragments) ----
  {
    float cs[4];
#pragma unroll
    for (int tc = 0; tc < 4; ++tc) {
      cs[tc] = acc[tc][0] + acc[tc][1] + acc[tc][2] + acc[tc][3];
      cs[tc] += __shfl_xor(cs[tc], 16, 64);
      cs[tc] += __shfl_xor(cs[tc], 32, 64);
    }
    if (lane < 16) {
#pragma unroll
      for (int tc = 0; tc < 4; ++tc) molp[w][tc * 16 + lane] = cs[tc];
    }
  }
  __syncthreads();
  if (t < 64) mol_s[t] = molp[0][t] + molp[1][t] + molp[2][t] + molp[3][t];
  __syncthreads();

  // ---- MLP head (f32, wave 0 computes, barriers keep block convergent) ----
  for (int l = 0; l < 3; ++l) {
    float a = 0.f;
    if (t < 64) {
      a = bo[l * DIM + t];
      const float* wl = Wo + l * DIM * DIM + t;
#pragma unroll 8
      for (int k = 0; k < DIM; ++k) a += mol_s[k] * wl[k * DIM];
      a = fmaxf(a, 0.f);
    }
    __syncthreads();
    if (t < 64) mol_s[t] = a;
    __syncthreads();
  }

  // ---- final projection to 452 props (all 256 threads) ----
  for (int p = t; p < NPROP; p += 256) {
    float a = bp[p];
    const float* wp = Wp + p;
#pragma unroll 8
    for (int k = 0; k < DIM; ++k) a += mol_s[k] * wp[k * NPROP];
    out[(size_t)b * NPROP + p] = a;
  }
}

extern "C" void kernel_launch(void* const* d_in, const int* in_sizes, int n_in,
                              void* d_out, int out_size, void* d_ws, size_t ws_size,
                              hipStream_t stream) {
  const int*   fp    = (const int*)d_in[0];
  const float* adj   = (const float*)d_in[1];
  // d_in[2] = mol_size (scalar, hardcoded 64)
  const float* embed = (const float*)d_in[3];
  const float* Wf    = (const float*)d_in[4];
  const float* bfv   = (const float*)d_in[5];
  const float* Wo    = (const float*)d_in[6];
  const float* bo    = (const float*)d_in[7];
  const float* Wp    = (const float*)d_in[8];
  const float* bp    = (const float*)d_in[9];
  float* out = (float*)d_out;
  mgnn_kernel<<<128, 256, 0, stream>>>(fp, adj, embed, Wf, bfv, Wo, bo, Wp, bp, out);
}